// Round 1
// baseline (235.087 us; speedup 1.0000x reference)
//
#include <hip/hip_runtime.h>

#define D 128
#define D4 32   // float4 per row

// ---------------- degree / dinv ----------------

__global__ void k_init(int* cnt, int* cursor, int n) {
    int i = blockIdx.x * blockDim.x + threadIdx.x;
    if (i < n) { cnt[i] = 0; cursor[i] = 0; }
}

__global__ void k_count(const int* dst, int* cnt, int e) {
    int i = blockIdx.x * blockDim.x + threadIdx.x;
    if (i < e) atomicAdd(&cnt[dst[i]], 1);
}

__global__ void k_dinv(const int* cnt, float* dinv, int n) {
    int i = blockIdx.x * blockDim.x + threadIdx.x;
    if (i < n) dinv[i] = rsqrtf((float)(cnt[i] + 1));
}

// ---------------- prefix scan (3-kernel) ----------------

__global__ void k_scan_block(const int* cnt, int* off, int* bsum, int n) {
    __shared__ int s[256];
    int t = threadIdx.x;
    int i = blockIdx.x * 256 + t;
    int v = (i < n) ? cnt[i] : 0;
    s[t] = v;
    __syncthreads();
    for (int d2 = 1; d2 < 256; d2 <<= 1) {
        int add = (t >= d2) ? s[t - d2] : 0;
        __syncthreads();
        s[t] += add;
        __syncthreads();
    }
    if (i < n) off[i] = s[t] - v;          // block-local exclusive
    if (t == 255) bsum[blockIdx.x] = s[255];
}

__global__ void k_scan_bsum(int* bsum, int nb) {
    __shared__ int s[512];
    int t = threadIdx.x;
    int v = (t < nb) ? bsum[t] : 0;
    s[t] = v;
    __syncthreads();
    for (int d2 = 1; d2 < 512; d2 <<= 1) {
        int add = (t >= d2) ? s[t - d2] : 0;
        __syncthreads();
        s[t] += add;
        __syncthreads();
    }
    if (t < nb) bsum[t] = s[t] - v;        // exclusive
}

__global__ void k_scan_add(int* off, const int* bsum, int n) {
    int i = blockIdx.x * 256 + threadIdx.x;
    if (i < n) off[i] += bsum[i >> 8];
}

// ---------------- edge permute (counting sort by dst) ----------------

__global__ void k_permute(const int* src, const int* dst, const int* off,
                          int* cursor, int* ssrc, int e) {
    int i = blockIdx.x * blockDim.x + threadIdx.x;
    if (i < e) {
        int d = dst[i];
        int p = off[d] + atomicAdd(&cursor[d], 1);
        ssrc[p] = src[i];
    }
}

// ---------------- gather: agg = D^{-1/2}(A+I)D^{-1/2} X  ->  out ----------------

__global__ __launch_bounds__(256) void k_gather(const float* x, const float* dinv,
                                                const int* off, const int* cnt,
                                                const int* ssrc, float* out, int n) {
    int gid = blockIdx.x * blockDim.x + threadIdx.x;
    int wid = gid >> 6;   // one wave per node
    int lane = gid & 63;
    if (wid >= n) return;
    float di = dinv[wid];
    const float2* xr = (const float2*)x;
    float2 xi = xr[(size_t)wid * 64 + lane];
    float w0 = di * di;
    float2 acc = make_float2(w0 * xi.x, w0 * xi.y);
    int s0 = off[wid];
    int m = cnt[wid];
    for (int j = 0; j < m; ++j) {
        int s = ssrc[s0 + j];
        float c = di * dinv[s];
        float2 xs = xr[(size_t)s * 64 + lane];
        acc.x += c * xs.x;
        acc.y += c * xs.y;
    }
    ((float2*)out)[(size_t)wid * 64 + lane] = acc;
}

// ---------------- atomic-scatter fallback (small ws) ----------------

__global__ void k_self(const float* x, const float* dinv, float* out, int n) {
    int gid = blockIdx.x * blockDim.x + threadIdx.x;  // over n*32 float4
    if (gid < n * D4) {
        int row = gid >> 5;
        float di = dinv[row];
        float w0 = di * di;
        float4 v = ((const float4*)x)[gid];
        v.x *= w0; v.y *= w0; v.z *= w0; v.w *= w0;
        ((float4*)out)[gid] = v;
    }
}

__global__ void k_scatter_atomic(const float* x, const int* src, const int* dst,
                                 const float* dinv, float* out, int e) {
    int gid = blockIdx.x * blockDim.x + threadIdx.x;  // e*32 threads
    int eid = gid >> 5, q = gid & 31;
    if (eid >= e) return;
    int s = src[eid], d = dst[eid];
    float c = dinv[s] * dinv[d];
    float4 v = ((const float4*)x)[(size_t)s * D4 + q];
    float* o = out + (size_t)d * D + q * 4;
    atomicAdd(o + 0, c * v.x);
    atomicAdd(o + 1, c * v.y);
    atomicAdd(o + 2, c * v.z);
    atomicAdd(o + 3, c * v.w);
}

// ---------------- in-place GEMM + bias + ReLU: io = relu(io @ W + b) ----------------

__global__ __launch_bounds__(512) void k_gemm_relu(float* io, const float* W,
                                                   const float* b, int n) {
    __shared__ float4 Wl[D * D4];  // 64 KB: W row-major as float4 [k][tx]
    int t = threadIdx.x;
    const float4* W4 = (const float4*)W;
#pragma unroll
    for (int q = 0; q < 8; ++q) Wl[t + q * 512] = W4[t + q * 512];
    __syncthreads();

    int tx = t & 31;       // col group: cols tx*4..tx*4+3
    int ty = t >> 5;       // row group: rows ty*8..ty*8+7
    int row0 = blockIdx.x * 128;

    const float4* a4 = (const float4*)io;
    int rb[8];
#pragma unroll
    for (int r = 0; r < 8; ++r) {
        int gr = row0 + ty * 8 + r;
        if (gr > n - 1) gr = n - 1;   // clamp stays within this block's rows
        rb[r] = gr * D4;
    }

    float4 bb = ((const float4*)b)[tx];
    float4 acc[8];
#pragma unroll
    for (int r = 0; r < 8; ++r) acc[r] = bb;

    for (int k4 = 0; k4 < 32; ++k4) {
        float4 a[8];
#pragma unroll
        for (int r = 0; r < 8; ++r) a[r] = a4[(size_t)rb[r] + k4];
#pragma unroll
        for (int kk = 0; kk < 4; ++kk) {
            float4 w = Wl[(k4 * 4 + kk) * D4 + tx];
#pragma unroll
            for (int r = 0; r < 8; ++r) {
                float av = (kk == 0) ? a[r].x : (kk == 1) ? a[r].y
                           : (kk == 2) ? a[r].z : a[r].w;
                acc[r].x += av * w.x;
                acc[r].y += av * w.y;
                acc[r].z += av * w.z;
                acc[r].w += av * w.w;
            }
        }
    }

    __syncthreads();  // all reads of io rows done before any in-place store
    float4* o4 = (float4*)io;
#pragma unroll
    for (int r = 0; r < 8; ++r) {
        int gr = row0 + ty * 8 + r;
        if (gr < n) {
            float4 v = acc[r];
            v.x = fmaxf(v.x, 0.f);
            v.y = fmaxf(v.y, 0.f);
            v.z = fmaxf(v.z, 0.f);
            v.w = fmaxf(v.w, 0.f);
            o4[(size_t)gr * D4 + tx] = v;
        }
    }
}

// ---------------- launch ----------------

extern "C" void kernel_launch(void* const* d_in, const int* in_sizes, int n_in,
                              void* d_out, int out_size, void* d_ws, size_t ws_size,
                              hipStream_t stream) {
    const float* x = (const float*)d_in[0];
    const int* ei = (const int*)d_in[1];
    const float* W = (const float*)d_in[2];
    const float* b = (const float*)d_in[3];
    float* out = (float*)d_out;

    int n = in_sizes[0] / D;   // 100000
    int e = in_sizes[1] / 2;   // 500000
    const int* src = ei;
    const int* dst = ei + e;

    char* ws = (char*)d_ws;
    size_t nB = (size_t)n * 4;                 // bytes per N-sized int/float array
    int* cnt    = (int*)(ws);
    int* cursor = (int*)(ws + nB);
    int* off    = (int*)(ws + 2 * nB);
    float* dinv = (float*)(ws + 3 * nB);
    int* bsum   = (int*)(ws + 4 * nB);         // 1024 ints
    int* ssrc   = (int*)(ws + 4 * nB + 4096);
    size_t need = 4 * nB + 4096 + (size_t)e * 4;

    int nb = (n + 255) / 256;                  // 391 (must be <= 512 for bsum scan)
    int eb = (e + 255) / 256;

    if (ws_size >= need && nb <= 512) {
        // CSR gather path
        k_init<<<nb, 256, 0, stream>>>(cnt, cursor, n);
        k_count<<<eb, 256, 0, stream>>>(dst, cnt, e);
        k_dinv<<<nb, 256, 0, stream>>>(cnt, dinv, n);
        k_scan_block<<<nb, 256, 0, stream>>>(cnt, off, bsum, n);
        k_scan_bsum<<<1, 512, 0, stream>>>(bsum, nb);
        k_scan_add<<<nb, 256, 0, stream>>>(off, bsum, n);
        k_permute<<<eb, 256, 0, stream>>>(src, dst, off, cursor, ssrc, e);
        int gblocks = (n * 64 + 255) / 256;
        k_gather<<<gblocks, 256, 0, stream>>>(x, dinv, off, cnt, ssrc, out, n);
    } else {
        // atomic-scatter fallback: needs only cnt + dinv (800 KB)
        float* dinv2 = (float*)(ws + nB);
        k_init<<<nb, 256, 0, stream>>>(cnt, cnt, n);
        k_count<<<eb, 256, 0, stream>>>(dst, cnt, e);
        k_dinv<<<nb, 256, 0, stream>>>(cnt, dinv2, n);
        k_self<<<(n * D4 + 255) / 256, 256, 0, stream>>>(x, dinv2, out, n);
        k_scatter_atomic<<<((size_t)e * D4 + 255) / 256, 256, 0, stream>>>(
            x, src, dst, dinv2, out, e);
    }

    // in-place: out = relu(out @ W + b)
    int gemm_blocks = (n + 127) / 128;
    k_gemm_relu<<<gemm_blocks, 512, 0, stream>>>(out, W, b, n);
}

// Round 2
// 148.842 us; speedup vs baseline: 1.5794x; 1.5794x over previous
//
#include <hip/hip_runtime.h>

#define D 128

typedef __attribute__((ext_vector_type(8))) short bf16x8;
typedef __attribute__((ext_vector_type(4))) float f32x4;

__device__ __forceinline__ unsigned short f2bf(float f) {
    unsigned int u = __float_as_uint(f);
    unsigned int r = (u + 0x7fffu + ((u >> 16) & 1u)) >> 16;
    return (unsigned short)r;
}

// ---------------- preprocessing ----------------

__global__ void k_init(int* cnt, int* cursor, int n, const float* W, unsigned short* Wb) {
    int i = blockIdx.x * blockDim.x + threadIdx.x;
    if (i < n) { cnt[i] = 0; cursor[i] = 0; }
    if (i < D * D) Wb[i] = f2bf(W[i]);
}

__global__ void k_count(const int* dst, int* cnt, int e) {
    int i = blockIdx.x * blockDim.x + threadIdx.x;
    if (i < e) atomicAdd(&cnt[dst[i]], 1);
}

// block-local exclusive scan; also computes dinv = rsqrt(deg+1)
__global__ void k_scan_block(const int* cnt, int* off, int* bsum, float* dinv, int n) {
    __shared__ int s[256];
    int t = threadIdx.x;
    int i = blockIdx.x * 256 + t;
    int v = (i < n) ? cnt[i] : 0;
    if (i < n) dinv[i] = rsqrtf((float)(v + 1));
    s[t] = v;
    __syncthreads();
    for (int d2 = 1; d2 < 256; d2 <<= 1) {
        int add = (t >= d2) ? s[t - d2] : 0;
        __syncthreads();
        s[t] += add;
        __syncthreads();
    }
    if (i < n) off[i] = s[t] - v;
    if (t == 255) bsum[blockIdx.x] = s[255];
}

__global__ void k_scan_bsum(int* bsum, int nb) {
    __shared__ int s[512];
    int t = threadIdx.x;
    int v = (t < nb) ? bsum[t] : 0;
    s[t] = v;
    __syncthreads();
    for (int d2 = 1; d2 < 512; d2 <<= 1) {
        int add = (t >= d2) ? s[t - d2] : 0;
        __syncthreads();
        s[t] += add;
        __syncthreads();
    }
    if (t < nb) bsum[t] = s[t] - v;
}

__global__ void k_scan_add(int* off, const int* bsum, int n) {
    int i = blockIdx.x * 256 + threadIdx.x;
    if (i < n) off[i] += bsum[i >> 8];
}

__global__ void k_permute(const int* src, const int* dst, const int* off,
                          int* cursor, int* ssrc, int e) {
    int i = blockIdx.x * blockDim.x + threadIdx.x;
    if (i < e) {
        int d = dst[i];
        int p = off[d] + atomicAdd(&cursor[d], 1);
        ssrc[p] = src[i];
    }
}

// ---------------- h = x @ W  (bf16 MFMA, h stored bf16) ----------------
// block: 512 threads = 8 waves, 128 rows/block; W^T staged in LDS (swizzled)

__global__ __launch_bounds__(512) void k_gemm_h(const float* __restrict__ x,
                                                const unsigned short* __restrict__ Wb,
                                                unsigned short* __restrict__ h, int n) {
    __shared__ __align__(16) unsigned short Wt[D * D];  // [col][k^swz], 32 KB
    int t = threadIdx.x;
#pragma unroll
    for (int i = 0; i < 32; ++i) {
        int e = t + i * 512;
        int k = e >> 7, nn = e & 127;
        Wt[nn * D + (k ^ ((nn & 7) << 3))] = Wb[e];
    }
    __syncthreads();

    int wave = t >> 6, lane = t & 63;
    int lr = lane & 15;              // A-row / B-col within tile
    int lk = (lane >> 4) << 3;       // k sub-offset: 0,8,16,24
    int row = blockIdx.x * 128 + wave * 16 + lr;
    int rclamp = row < n ? row : n - 1;

    bf16x8 afrag[4];
    const float* xr = x + (size_t)rclamp * D;
#pragma unroll
    for (int kt = 0; kt < 4; ++kt) {
        int k0 = kt * 32 + lk;
        float4 lo = *(const float4*)(xr + k0);
        float4 hi = *(const float4*)(xr + k0 + 4);
        bf16x8 a;
        a[0] = f2bf(lo.x); a[1] = f2bf(lo.y); a[2] = f2bf(lo.z); a[3] = f2bf(lo.w);
        a[4] = f2bf(hi.x); a[5] = f2bf(hi.y); a[6] = f2bf(hi.z); a[7] = f2bf(hi.w);
        afrag[kt] = a;
    }

    int orow0 = blockIdx.x * 128 + wave * 16 + ((lane >> 4) << 2);
#pragma unroll
    for (int c = 0; c < 8; ++c) {
        f32x4 acc = {0.f, 0.f, 0.f, 0.f};
        int col = c * 16 + lr;
#pragma unroll
        for (int kt = 0; kt < 4; ++kt) {
            int k0 = kt * 32 + lk;
            bf16x8 bfr = *(const bf16x8*)&Wt[col * D + (k0 ^ ((col & 7) << 3))];
            acc = __builtin_amdgcn_mfma_f32_16x16x32_bf16(afrag[kt], bfr, acc, 0, 0, 0);
        }
#pragma unroll
        for (int r = 0; r < 4; ++r) {
            int orow = orow0 + r;
            if (orow < n) h[(size_t)orow * D + col] = f2bf(acc[r]);
        }
    }
}

// ---------------- gather: out = relu(D^{-1/2}(A+I)D^{-1/2} h + b) ----------------

__global__ __launch_bounds__(256) void k_gather(const unsigned short* __restrict__ h,
                                                const float* __restrict__ dinv,
                                                const int* __restrict__ off,
                                                const int* __restrict__ cnt,
                                                const int* __restrict__ ssrc,
                                                const float* __restrict__ b,
                                                float* __restrict__ out, int n) {
    int gid = blockIdx.x * blockDim.x + threadIdx.x;
    int wid = gid >> 6, lane = gid & 63;
    if (wid >= n) return;
    float di = dinv[wid];
    const unsigned int* hr = (const unsigned int*)h;
    unsigned int u = hr[(size_t)wid * 64 + lane];
    float w0 = di * di;
    float a0 = w0 * __uint_as_float(u << 16);
    float a1 = w0 * __uint_as_float(u & 0xffff0000u);
    int s0 = off[wid], m = cnt[wid];
    for (int j = 0; j < m; ++j) {
        int s = ssrc[s0 + j];
        float c = di * dinv[s];
        unsigned int v = hr[(size_t)s * 64 + lane];
        a0 += c * __uint_as_float(v << 16);
        a1 += c * __uint_as_float(v & 0xffff0000u);
    }
    float2 bb = ((const float2*)b)[lane];
    a0 = fmaxf(a0 + bb.x, 0.f);
    a1 = fmaxf(a1 + bb.y, 0.f);
    ((float2*)out)[(size_t)wid * 64 + lane] = make_float2(a0, a1);
}

// ---------------- fp32 fallback (small ws): atomic scatter ----------------

__global__ void k_dinv_only(const int* cnt, float* dinv, int n) {
    int i = blockIdx.x * blockDim.x + threadIdx.x;
    if (i < n) dinv[i] = rsqrtf((float)(cnt[i] + 1));
}

__global__ void k_self(const float* x, const float* dinv, float* out, int n) {
    int gid = blockIdx.x * blockDim.x + threadIdx.x;
    if (gid < n * 32) {
        int row = gid >> 5;
        float di = dinv[row];
        float w0 = di * di;
        float4 v = ((const float4*)x)[gid];
        v.x *= w0; v.y *= w0; v.z *= w0; v.w *= w0;
        ((float4*)out)[gid] = v;
    }
}

__global__ void k_scatter_atomic(const float* x, const int* src, const int* dst,
                                 const float* dinv, float* out, int e) {
    int gid = blockIdx.x * blockDim.x + threadIdx.x;
    int eid = gid >> 5, q = gid & 31;
    if (eid >= e) return;
    int s = src[eid], d = dst[eid];
    float c = dinv[s] * dinv[d];
    float4 v = ((const float4*)x)[(size_t)s * 32 + q];
    float* o = out + (size_t)d * D + q * 4;
    atomicAdd(o + 0, c * v.x);
    atomicAdd(o + 1, c * v.y);
    atomicAdd(o + 2, c * v.z);
    atomicAdd(o + 3, c * v.w);
}

__global__ __launch_bounds__(512) void k_gemm_relu(float* io, const float* W,
                                                   const float* b, int n) {
    __shared__ float4 Wl[D * 32];
    int t = threadIdx.x;
    const float4* W4 = (const float4*)W;
#pragma unroll
    for (int q = 0; q < 8; ++q) Wl[t + q * 512] = W4[t + q * 512];
    __syncthreads();
    int tx = t & 31, ty = t >> 5;
    int row0 = blockIdx.x * 128;
    const float4* a4 = (const float4*)io;
    int rb[8];
#pragma unroll
    for (int r = 0; r < 8; ++r) {
        int gr = row0 + ty * 8 + r;
        if (gr > n - 1) gr = n - 1;
        rb[r] = gr * 32;
    }
    float4 bb = ((const float4*)b)[tx];
    float4 acc[8];
#pragma unroll
    for (int r = 0; r < 8; ++r) acc[r] = bb;
    for (int k4 = 0; k4 < 32; ++k4) {
        float4 a[8];
#pragma unroll
        for (int r = 0; r < 8; ++r) a[r] = a4[(size_t)rb[r] + k4];
#pragma unroll
        for (int kk = 0; kk < 4; ++kk) {
            float4 w = Wl[(k4 * 4 + kk) * 32 + tx];
#pragma unroll
            for (int r = 0; r < 8; ++r) {
                float av = (kk == 0) ? a[r].x : (kk == 1) ? a[r].y
                           : (kk == 2) ? a[r].z : a[r].w;
                acc[r].x += av * w.x;
                acc[r].y += av * w.y;
                acc[r].z += av * w.z;
                acc[r].w += av * w.w;
            }
        }
    }
    __syncthreads();
    float4* o4 = (float4*)io;
#pragma unroll
    for (int r = 0; r < 8; ++r) {
        int gr = row0 + ty * 8 + r;
        if (gr < n) {
            float4 v = acc[r];
            v.x = fmaxf(v.x, 0.f); v.y = fmaxf(v.y, 0.f);
            v.z = fmaxf(v.z, 0.f); v.w = fmaxf(v.w, 0.f);
            o4[(size_t)gr * 32 + tx] = v;
        }
    }
}

// ---------------- launch ----------------

extern "C" void kernel_launch(void* const* d_in, const int* in_sizes, int n_in,
                              void* d_out, int out_size, void* d_ws, size_t ws_size,
                              hipStream_t stream) {
    const float* x = (const float*)d_in[0];
    const int* ei = (const int*)d_in[1];
    const float* W = (const float*)d_in[2];
    const float* b = (const float*)d_in[3];
    float* out = (float*)d_out;

    int n = in_sizes[0] / D;
    int e = in_sizes[1] / 2;
    const int* src = ei;
    const int* dst = ei + e;

    char* ws = (char*)d_ws;
    size_t nB = (size_t)n * 4;
    int* cnt    = (int*)(ws);
    int* cursor = (int*)(ws + nB);
    int* off    = (int*)(ws + 2 * nB);
    float* dinv = (float*)(ws + 3 * nB);
    int* bsum   = (int*)(ws + 4 * nB);                       // 2 KB used
    unsigned short* Wb = (unsigned short*)(ws + 4 * nB + 4096);  // 32 KB
    int* ssrc   = (int*)(ws + 4 * nB + 4096 + 32768);
    unsigned short* h = (unsigned short*)(ws + 4 * nB + 4096 + 32768 + (size_t)e * 4);
    size_t need = 4 * nB + 4096 + 32768 + (size_t)e * 4 + (size_t)n * D * 2;

    int nb = (n + 255) / 256;
    int eb = (e + 255) / 256;

    if (ws_size >= need && nb <= 512) {
        k_init<<<nb, 256, 0, stream>>>(cnt, cursor, n, W, Wb);
        k_count<<<eb, 256, 0, stream>>>(dst, cnt, e);
        k_scan_block<<<nb, 256, 0, stream>>>(cnt, off, bsum, dinv, n);
        k_scan_bsum<<<1, 512, 0, stream>>>(bsum, nb);
        k_scan_add<<<nb, 256, 0, stream>>>(off, bsum, n);
        k_permute<<<eb, 256, 0, stream>>>(src, dst, off, cursor, ssrc, e);
        k_gemm_h<<<(n + 127) / 128, 512, 0, stream>>>(x, Wb, h, n);
        int gblocks = (n * 64 + 255) / 256;
        k_gather<<<gblocks, 256, 0, stream>>>(h, dinv, off, cnt, ssrc, b, out, n);
    } else {
        // fp32 atomic-scatter fallback (needs only 800 KB ws)
        float* dinv2 = (float*)(ws + nB);
        k_init<<<nb, 256, 0, stream>>>(cnt, cnt, n, W, (unsigned short*)(ws + 2 * nB));
        k_count<<<eb, 256, 0, stream>>>(dst, cnt, e);
        k_dinv_only<<<nb, 256, 0, stream>>>(cnt, dinv2, n);
        k_self<<<(n * 32 + 255) / 256, 256, 0, stream>>>(x, dinv2, out, n);
        k_scatter_atomic<<<((size_t)e * 32 + 255) / 256, 256, 0, stream>>>(
            x, src, dst, dinv2, out, e);
        k_gemm_relu<<<(n + 127) / 128, 512, 0, stream>>>(out, W, b, n);
    }
}

// Round 3
// 122.515 us; speedup vs baseline: 1.9188x; 1.2149x over previous
//
#include <hip/hip_runtime.h>

#define D 128

typedef __attribute__((ext_vector_type(8))) short bf16x8;
typedef __attribute__((ext_vector_type(4))) float f32x4;

__device__ __forceinline__ unsigned short f2bf(float f) {
    unsigned int u = __float_as_uint(f);
    unsigned int r = (u + 0x7fffu + ((u >> 16) & 1u)) >> 16;
    return (unsigned short)r;
}

// ---------------- preprocessing ----------------

__global__ void k_count(const int* dst, int* cnt, int e) {
    int i = blockIdx.x * blockDim.x + threadIdx.x;
    if (i < e) atomicAdd(&cnt[dst[i]], 1);
}

// block-local exclusive scan; also computes dinv = rsqrt(deg+1)
__global__ void k_scan_block(const int* cnt, int* off, int* bsum, float* dinv, int n) {
    __shared__ int s[256];
    int t = threadIdx.x;
    int i = blockIdx.x * 256 + t;
    int v = (i < n) ? cnt[i] : 0;
    if (i < n) dinv[i] = rsqrtf((float)(v + 1));
    s[t] = v;
    __syncthreads();
    for (int d2 = 1; d2 < 256; d2 <<= 1) {
        int add = (t >= d2) ? s[t - d2] : 0;
        __syncthreads();
        s[t] += add;
        __syncthreads();
    }
    if (i < n) off[i] = s[t] - v;
    if (t == 255) bsum[blockIdx.x] = s[255];
}

__global__ void k_scan_bsum(int* bsum, int nb) {
    __shared__ int s[512];
    int t = threadIdx.x;
    int v = (t < nb) ? bsum[t] : 0;
    s[t] = v;
    __syncthreads();
    for (int d2 = 1; d2 < 512; d2 <<= 1) {
        int add = (t >= d2) ? s[t - d2] : 0;
        __syncthreads();
        s[t] += add;
        __syncthreads();
    }
    if (t < nb) bsum[t] = s[t] - v;
}

__global__ void k_scan_add(int* off, const int* bsum, int n) {
    int i = blockIdx.x * 256 + threadIdx.x;
    if (i < n) off[i] += bsum[i >> 8];
}

__global__ void k_permute(const int* src, const int* dst, const int* off,
                          int* cursor, int* ssrc, int e) {
    int i = blockIdx.x * blockDim.x + threadIdx.x;
    if (i < e) {
        int d = dst[i];
        int p = off[d] + atomicAdd(&cursor[d], 1);
        ssrc[p] = src[i];
    }
}

// ---------------- h_scaled = dinv * (x @ W)  (bf16 MFMA) ----------------

__global__ __launch_bounds__(512) void k_gemm_h(const float* __restrict__ x,
                                                const float* __restrict__ W,
                                                const float* __restrict__ dinv,
                                                unsigned short* __restrict__ h, int n) {
    __shared__ __align__(16) unsigned short Wt[D * D];  // [col][k^swz], 32 KB
    int t = threadIdx.x;
#pragma unroll
    for (int i = 0; i < 32; ++i) {
        int e = t + i * 512;
        int k = e >> 7, nn = e & 127;
        Wt[nn * D + (k ^ ((nn & 7) << 3))] = f2bf(W[e]);
    }
    __syncthreads();

    int wave = t >> 6, lane = t & 63;
    int lr = lane & 15;              // A-row / B-col within tile
    int lk = (lane >> 4) << 3;       // k sub-offset: 0,8,16,24
    int row = blockIdx.x * 128 + wave * 16 + lr;
    int rclamp = row < n ? row : n - 1;

    bf16x8 afrag[4];
    const float* xr = x + (size_t)rclamp * D;
#pragma unroll
    for (int kt = 0; kt < 4; ++kt) {
        int k0 = kt * 32 + lk;
        float4 lo = *(const float4*)(xr + k0);
        float4 hi = *(const float4*)(xr + k0 + 4);
        bf16x8 a;
        a[0] = f2bf(lo.x); a[1] = f2bf(lo.y); a[2] = f2bf(lo.z); a[3] = f2bf(lo.w);
        a[4] = f2bf(hi.x); a[5] = f2bf(hi.y); a[6] = f2bf(hi.z); a[7] = f2bf(hi.w);
        afrag[kt] = a;
    }

    int orow0 = blockIdx.x * 128 + wave * 16 + ((lane >> 4) << 2);
    float dv[4];
#pragma unroll
    for (int r = 0; r < 4; ++r) {
        int orow = orow0 + r;
        dv[r] = dinv[orow < n ? orow : n - 1];
    }

#pragma unroll
    for (int c = 0; c < 8; ++c) {
        f32x4 acc = {0.f, 0.f, 0.f, 0.f};
        int col = c * 16 + lr;
#pragma unroll
        for (int kt = 0; kt < 4; ++kt) {
            int k0 = kt * 32 + lk;
            bf16x8 bfr = *(const bf16x8*)&Wt[col * D + (k0 ^ ((col & 7) << 3))];
            acc = __builtin_amdgcn_mfma_f32_16x16x32_bf16(afrag[kt], bfr, acc, 0, 0, 0);
        }
#pragma unroll
        for (int r = 0; r < 4; ++r) {
            int orow = orow0 + r;
            if (orow < n) h[(size_t)orow * D + col] = f2bf(acc[r] * dv[r]);
        }
    }
}

// ---------------- gather: out = relu(dinv[dst] * sum(h_scaled) + b) ----------------

__global__ __launch_bounds__(256) void k_gather(const unsigned short* __restrict__ h,
                                                const float* __restrict__ dinv,
                                                const int* __restrict__ off,
                                                const int* __restrict__ cnt,
                                                const int* __restrict__ ssrc,
                                                const float* __restrict__ b,
                                                float* __restrict__ out, int n) {
    int gid = blockIdx.x * blockDim.x + threadIdx.x;
    int wid = gid >> 6, lane = gid & 63;
    if (wid >= n) return;
    float di = dinv[wid];
    const unsigned int* hr = (const unsigned int*)h;
    unsigned int u = hr[(size_t)wid * 64 + lane];   // self term (h already dinv-scaled)
    float a0 = __uint_as_float(u << 16);
    float a1 = __uint_as_float(u & 0xffff0000u);
    int s0 = off[wid], m = cnt[wid];

    for (int j = 0; j < m; j += 8) {
        unsigned int v[8];
        float w[8];
#pragma unroll
        for (int k = 0; k < 8; ++k) {
            int jk = j + k;
            int idx = jk < m ? jk : m - 1;
            int s = ssrc[s0 + idx];
            v[k] = hr[(size_t)s * 64 + lane];
            w[k] = jk < m ? 1.f : 0.f;
        }
#pragma unroll
        for (int k = 0; k < 8; ++k) {
            a0 = fmaf(w[k], __uint_as_float(v[k] << 16), a0);
            a1 = fmaf(w[k], __uint_as_float(v[k] & 0xffff0000u), a1);
        }
    }

    float2 bb = ((const float2*)b)[lane];
    a0 = fmaxf(fmaf(di, a0, bb.x), 0.f);
    a1 = fmaxf(fmaf(di, a1, bb.y), 0.f);
    ((float2*)out)[(size_t)wid * 64 + lane] = make_float2(a0, a1);
}

// ---------------- fp32 fallback (small ws): atomic scatter ----------------

__global__ void k_dinv_only(const int* cnt, float* dinv, int n) {
    int i = blockIdx.x * blockDim.x + threadIdx.x;
    if (i < n) dinv[i] = rsqrtf((float)(cnt[i] + 1));
}

__global__ void k_self(const float* x, const float* dinv, float* out, int n) {
    int gid = blockIdx.x * blockDim.x + threadIdx.x;
    if (gid < n * 32) {
        int row = gid >> 5;
        float di = dinv[row];
        float w0 = di * di;
        float4 v = ((const float4*)x)[gid];
        v.x *= w0; v.y *= w0; v.z *= w0; v.w *= w0;
        ((float4*)out)[gid] = v;
    }
}

__global__ void k_scatter_atomic(const float* x, const int* src, const int* dst,
                                 const float* dinv, float* out, int e) {
    int gid = blockIdx.x * blockDim.x + threadIdx.x;
    int eid = gid >> 5, q = gid & 31;
    if (eid >= e) return;
    int s = src[eid], d = dst[eid];
    float c = dinv[s] * dinv[d];
    float4 v = ((const float4*)x)[(size_t)s * 32 + q];
    float* o = out + (size_t)d * D + q * 4;
    atomicAdd(o + 0, c * v.x);
    atomicAdd(o + 1, c * v.y);
    atomicAdd(o + 2, c * v.z);
    atomicAdd(o + 3, c * v.w);
}

__global__ __launch_bounds__(512) void k_gemm_relu(float* io, const float* W,
                                                   const float* b, int n) {
    __shared__ float4 Wl[D * 32];
    int t = threadIdx.x;
    const float4* W4 = (const float4*)W;
#pragma unroll
    for (int q = 0; q < 8; ++q) Wl[t + q * 512] = W4[t + q * 512];
    __syncthreads();
    int tx = t & 31, ty = t >> 5;
    int row0 = blockIdx.x * 128;
    const float4* a4 = (const float4*)io;
    int rb[8];
#pragma unroll
    for (int r = 0; r < 8; ++r) {
        int gr = row0 + ty * 8 + r;
        if (gr > n - 1) gr = n - 1;
        rb[r] = gr * 32;
    }
    float4 bb = ((const float4*)b)[tx];
    float4 acc[8];
#pragma unroll
    for (int r = 0; r < 8; ++r) acc[r] = bb;
    for (int k4 = 0; k4 < 32; ++k4) {
        float4 a[8];
#pragma unroll
        for (int r = 0; r < 8; ++r) a[r] = a4[(size_t)rb[r] + k4];
#pragma unroll
        for (int kk = 0; kk < 4; ++kk) {
            float4 w = Wl[(k4 * 4 + kk) * 32 + tx];
#pragma unroll
            for (int r = 0; r < 8; ++r) {
                float av = (kk == 0) ? a[r].x : (kk == 1) ? a[r].y
                           : (kk == 2) ? a[r].z : a[r].w;
                acc[r].x += av * w.x;
                acc[r].y += av * w.y;
                acc[r].z += av * w.z;
                acc[r].w += av * w.w;
            }
        }
    }
    __syncthreads();
    float4* o4 = (float4*)io;
#pragma unroll
    for (int r = 0; r < 8; ++r) {
        int gr = row0 + ty * 8 + r;
        if (gr < n) {
            float4 v = acc[r];
            v.x = fmaxf(v.x, 0.f); v.y = fmaxf(v.y, 0.f);
            v.z = fmaxf(v.z, 0.f); v.w = fmaxf(v.w, 0.f);
            o4[(size_t)gr * 32 + tx] = v;
        }
    }
}

// ---------------- launch ----------------

extern "C" void kernel_launch(void* const* d_in, const int* in_sizes, int n_in,
                              void* d_out, int out_size, void* d_ws, size_t ws_size,
                              hipStream_t stream) {
    const float* x = (const float*)d_in[0];
    const int* ei = (const int*)d_in[1];
    const float* W = (const float*)d_in[2];
    const float* b = (const float*)d_in[3];
    float* out = (float*)d_out;

    int n = in_sizes[0] / D;
    int e = in_sizes[1] / 2;
    const int* src = ei;
    const int* dst = ei + e;

    char* ws = (char*)d_ws;
    size_t nB = (size_t)n * 4;
    int* cnt    = (int*)(ws);
    int* cursor = (int*)(ws + nB);
    int* off    = (int*)(ws + 2 * nB);
    float* dinv = (float*)(ws + 3 * nB);
    int* bsum   = (int*)(ws + 4 * nB);                         // 4 KB reserved
    int* ssrc   = (int*)(ws + 4 * nB + 4096);
    unsigned short* h = (unsigned short*)(ws + 4 * nB + 4096 + (size_t)e * 4);
    size_t need = 4 * nB + 4096 + (size_t)e * 4 + (size_t)n * D * 2;

    int nb = (n + 255) / 256;
    int eb = (e + 255) / 256;

    if (ws_size >= need && nb <= 512) {
        hipMemsetAsync(ws, 0, 2 * nB, stream);                 // cnt + cursor
        k_count<<<eb, 256, 0, stream>>>(dst, cnt, e);
        k_scan_block<<<nb, 256, 0, stream>>>(cnt, off, bsum, dinv, n);
        k_scan_bsum<<<1, 512, 0, stream>>>(bsum, nb);
        k_scan_add<<<nb, 256, 0, stream>>>(off, bsum, n);
        k_permute<<<eb, 256, 0, stream>>>(src, dst, off, cursor, ssrc, e);
        k_gemm_h<<<(n + 127) / 128, 512, 0, stream>>>(x, W, dinv, h, n);
        int gblocks = (n * 64 + 255) / 256;
        k_gather<<<gblocks, 256, 0, stream>>>(h, dinv, off, cnt, ssrc, b, out, n);
    } else {
        // fp32 atomic-scatter fallback (needs only 800 KB ws)
        float* dinv2 = (float*)(ws + nB);
        hipMemsetAsync(ws, 0, nB, stream);
        k_count<<<eb, 256, 0, stream>>>(dst, cnt, e);
        k_dinv_only<<<nb, 256, 0, stream>>>(cnt, dinv2, n);
        k_self<<<(n * 32 + 255) / 256, 256, 0, stream>>>(x, dinv2, out, n);
        k_scatter_atomic<<<((size_t)e * 32 + 255) / 256, 256, 0, stream>>>(
            x, src, dst, dinv2, out, e);
        k_gemm_relu<<<(n + 127) / 128, 512, 0, stream>>>(out, W, b, n);
    }
}